// Round 8
// baseline (612.523 us; speedup 1.0000x reference)
//
#include <hip/hip_runtime.h>

// features: (16, 64, 65536) f32, coords: (16, 3, 65536) f32, resolution = 32
constexpr int Rr = 32;
constexpr int R2 = Rr * Rr;          // 1024
constexpr int R3 = Rr * Rr * Rr;     // 32768
constexpr int Bb = 16;
constexpr int Cc = 64;
constexpr int Nn = 65536;
constexpr int VOX_ELEMS = Bb * Cc * R3;    // 33,554,432
constexpr int NCELL  = Bb * R3;            // 524,288
constexpr int NSLOTS = Bb * Nn;            // 1,048,576
constexpr int SRANGE = 64;                 // slots per wave in streamaccum

// ---------------- K1: norm_coords + voxel idx + int counts ----------------
__global__ __launch_bounds__(256) void vox_coords_kernel(
    const float* __restrict__ coords,
    float* __restrict__ norm_out,
    int* __restrict__ idx_out,
    int* __restrict__ cnt)
{
    int t = blockIdx.x * 256 + threadIdx.x;        // t = b*N + i
    int b = t >> 16;
    int i = t & (Nn - 1);

    const float* cp = coords + (size_t)b * 3 * Nn + i;
    float x = cp[0];
    float y = cp[Nn];
    float z = cp[2 * Nn];

    float nx = fminf(fmaxf((x + 1.0f) * 16.0f, 0.0f), 31.0f);
    float ny = fminf(fmaxf((y + 1.0f) * 16.0f, 0.0f), 31.0f);
    float nz = fminf(fmaxf((z + 1.0f) * 16.0f, 0.0f), 31.0f);

    float* np_ = norm_out + (size_t)b * 3 * Nn + i;
    np_[0]      = nx;
    np_[Nn]     = ny;
    np_[2 * Nn] = nz;

    int idx = (int)rintf(nx) * R2 + (int)rintf(ny) * Rr + (int)rintf(nz);

    idx_out[t] = idx;
    atomicAdd(&cnt[(b << 15) + idx], 1);
}

// ---------------- Scan phase 1 ----------------
__global__ __launch_bounds__(256) void scan1_kernel(
    const int* __restrict__ cnt, int* __restrict__ cursor, int* __restrict__ bsums)
{
    __shared__ int sm[256];
    int t = blockIdx.x * 256 + threadIdx.x;
    int v = cnt[t];
    sm[threadIdx.x] = v;
    __syncthreads();
#pragma unroll
    for (int off = 1; off < 256; off <<= 1) {
        int x = (threadIdx.x >= off) ? sm[threadIdx.x - off] : 0;
        __syncthreads();
        sm[threadIdx.x] += x;
        __syncthreads();
    }
    cursor[t] = sm[threadIdx.x] - v;
    if (threadIdx.x == 255) bsums[blockIdx.x] = sm[255];
}

// ---------------- Scan phase 2 ----------------
__global__ __launch_bounds__(256) void scan2_kernel(int* __restrict__ bsums)
{
    __shared__ int sm[256];
    int carry = 0;
    for (int chunk = 0; chunk < 2048; chunk += 256) {
        int v = bsums[chunk + threadIdx.x];
        sm[threadIdx.x] = v;
        __syncthreads();
#pragma unroll
        for (int off = 1; off < 256; off <<= 1) {
            int x = (threadIdx.x >= off) ? sm[threadIdx.x - off] : 0;
            __syncthreads();
            sm[threadIdx.x] += x;
            __syncthreads();
        }
        bsums[chunk + threadIdx.x] = carry + sm[threadIdx.x] - v;
        carry += sm[255];
        __syncthreads();
    }
}

// ---------------- Scan phase 3 ----------------
__global__ __launch_bounds__(256) void scan3_kernel(
    int* __restrict__ cursor, const int* __restrict__ bsums)
{
    int t = blockIdx.x * 256 + threadIdx.x;
    cursor[t] += bsums[blockIdx.x];
}

// ---------------- Binning: slotbuf[t] = idx on entry, slot on exit ----------------
__global__ __launch_bounds__(256) void bin_kernel(
    int* __restrict__ slotbuf, int* __restrict__ cursor, int* __restrict__ packed)
{
    int t = blockIdx.x * 256 + threadIdx.x;
    int b = t >> 16;
    int i = t & (Nn - 1);
    int idx = slotbuf[t];                                // read idx
    int slot = atomicAdd(&cursor[(b << 15) + idx], 1);   // L2-resident 2 MB table
    packed[slot] = (idx << 16) | i;                      // 15b cell | 16b pid
    slotbuf[t] = slot;                                   // overwrite with slot
}

// ---------------- K2: counts -> inverse (empty -> 0 so garbage*0 = +-0) ----------------
__global__ __launch_bounds__(256) void inv_kernel(
    const int* __restrict__ cnt, float* __restrict__ inv)
{
    int t = blockIdx.x * 256 + threadIdx.x;        // total NCELL
    int c = cnt[t];
    inv[t] = c ? 1.0f / (float)c : 0.0f;
}

// ---------------- Transpose + scatter: feat (b,c,n) -> featS[slot][c] ----------------
__global__ __launch_bounds__(256) void tscatter_kernel(
    const float* __restrict__ feat, const int* __restrict__ slotbuf,
    float* __restrict__ featS)
{
    __shared__ float lds[64 * 65];                 // [n][c], stride 65
    __shared__ int   slot_sm[64];
    int b    = blockIdx.x >> 10;
    int tile = blockIdx.x & 1023;
    int n0   = tile << 6;
    int t    = threadIdx.x;

    if (t < 64) slot_sm[t] = slotbuf[(b << 16) + n0 + t];

#pragma unroll
    for (int k = 0; k < 4; ++k) {
        int c  = (t >> 4) + (k << 4);
        int n4 = (t & 15) << 2;
        float4 v = *(const float4*)(feat + (((size_t)(b * Cc + c)) << 16) + n0 + n4);
        lds[(n4 + 0) * 65 + c] = v.x;
        lds[(n4 + 1) * 65 + c] = v.y;
        lds[(n4 + 2) * 65 + c] = v.z;
        lds[(n4 + 3) * 65 + c] = v.w;
    }
    __syncthreads();

    // each wave writes 16 point-rows: 64 lanes x 4B = one 256 B segment per store
    int wave = t >> 6, lane = t & 63;
#pragma unroll
    for (int k = 0; k < 16; ++k) {
        int n = (wave << 4) + k;
        float v = lds[n * 65 + lane];
        featS[((size_t)slot_sm[n] << 6) + lane] = v;   // random but aligned 256 B row
    }
}

// ---------------- Streamaccum: fixed 64-slot range per wave, register acc ----------------
__global__ __launch_bounds__(256) void streamaccum_kernel(
    const float* __restrict__ featS,
    const int* __restrict__ packed,
    float* __restrict__ vox,
    float* __restrict__ trash)
{
    int wgid = blockIdx.x * 4 + (threadIdx.x >> 6);   // global wave id
    int lane = threadIdx.x & 63;
    int s0   = wgid * SRANGE;

    // first boundary >= from (boundary at p: batch start or cell-id change)
    auto find_bnd = [&](int from) -> int {
        for (int base = from; ; base += 64) {
            int p = base + lane;
            int cur = packed[p] >> 16;
            int prv = packed[p - 1] >> 16;
            bool bnd = ((p & 65535) == 0) || (cur != prv);
            unsigned long long m = __ballot(bnd);
            if (m) return base + (int)__ffsll((unsigned long long)m) - 1;
        }
    };
    int ts = find_bnd(s0);                 // wave k's ts == wave k-1's te (same formula)
    int te = find_bnd(s0 + SRANGE);

    float* tr = trash + ((size_t)(blockIdx.x) << 6) + lane;  // per-block L2-hot trash row
    float acc = 0.0f;

    for (int s = ts; s < te; s += 8) {
        int pk[9];
#pragma unroll
        for (int j = 0; j < 9; ++j) pk[j] = packed[s + j];   // uniform, sequential
        float f[8];
#pragma unroll
        for (int j = 0; j < 8; ++j)                          // affine 256B rows
            f[j] = featS[((size_t)(s + j) << 6) + lane];

#pragma unroll
        for (int j = 0; j < 8; ++j) {
            int  sj  = s + j;
            bool bnd = ((((sj + 1) & 65535) == 0) || ((pk[j] >> 16) != (pk[j + 1] >> 16)))
                       && (sj < te);                         // mask beyond-range slots
            float accn = acc + f[j];
            int v = (pk[j] >> 16) & 32767;
            int b = sj >> 16;
            float* addr = bnd ? (vox + ((((size_t)b << 6) + lane) << 15) + v) : tr;
            *addr = accn;                                    // always-store, branchless
            acc = bnd ? 0.0f : accn;
        }
    }
}

// ---------------- Scale: vox *= inv[cell]  (empty cells: garbage * 0 = +-0) ----------------
__global__ __launch_bounds__(256) void scale_kernel(
    float* __restrict__ vox, const float* __restrict__ inv)
{
    int e = (blockIdx.x * 256 + threadIdx.x) << 2;  // element quad
    int b = e >> 21;
    int v = e & 32767;
    float4 s  = *(float4*)(vox + e);
    float4 iv = *(const float4*)(inv + (b << 15) + v);
    s.x *= iv.x; s.y *= iv.y; s.z *= iv.z; s.w *= iv.w;
    *(float4*)(vox + e) = s;
}

extern "C" void kernel_launch(void* const* d_in, const int* in_sizes, int n_in,
                              void* d_out, int out_size, void* d_ws, size_t ws_size,
                              hipStream_t stream)
{
    const float* features = (const float*)d_in[0];
    const float* coords   = (const float*)d_in[1];

    float* out      = (float*)d_out;
    float* vox      = out;
    float* norm_out = out + VOX_ELEMS;

    // ws: cnt 2MB | cursor 2MB (reused as trash) | packed (+512 pad) | bsums | slotbuf 4MB | inv 2MB | featS 268MB
    char* ws = (char*)d_ws;
    int*   cnt     = (int*)ws;   ws += (size_t)NCELL * 4;
    int*   cursor  = (int*)ws;   ws += (size_t)NCELL * 4;       // trash aliases this after bin
    int*   packed  = (int*)ws;   ws += (size_t)(NSLOTS + 512) * 4;
    int*   bsums   = (int*)ws;   ws += 2048 * 4;
    int*   slotbuf = (int*)ws;   ws += (size_t)NSLOTS * 4;
    float* inv     = (float*)ws; ws += (size_t)NCELL * 4;
    float* featS   = (float*)ws;                                 // (NSLOTS+16) rows of 256B

    float* trash = (float*)cursor;   // cursor is dead after bin; 4096 blocks * 256B = 1 MB

    hipMemsetAsync(cnt, 0, (size_t)NCELL * sizeof(int), stream);

    vox_coords_kernel<<<(Bb * Nn) / 256, 256, 0, stream>>>(coords, norm_out, slotbuf, cnt);
    scan1_kernel<<<NCELL / 256, 256, 0, stream>>>(cnt, cursor, bsums);
    scan2_kernel<<<1, 256, 0, stream>>>(bsums);
    scan3_kernel<<<NCELL / 256, 256, 0, stream>>>(cursor, bsums);
    bin_kernel<<<(Bb * Nn) / 256, 256, 0, stream>>>(slotbuf, cursor, packed);
    inv_kernel<<<NCELL / 256, 256, 0, stream>>>(cnt, inv);

    tscatter_kernel<<<Bb * 1024, 256, 0, stream>>>(features, slotbuf, featS);
    streamaccum_kernel<<<NSLOTS / SRANGE / 4, 256, 0, stream>>>(featS, packed, vox, trash);
    scale_kernel<<<VOX_ELEMS / 4 / 256, 256, 0, stream>>>(vox, inv);
}

// Round 9
// 259.837 us; speedup vs baseline: 2.3573x; 2.3573x over previous
//
#include <hip/hip_runtime.h>

// features: (16, 64, 65536) f32, coords: (16, 3, 65536) f32, resolution = 32
constexpr int Rr = 32;
constexpr int R2 = Rr * Rr;          // 1024
constexpr int R3 = Rr * Rr * Rr;     // 32768
constexpr int Bb = 16;
constexpr int Cc = 64;
constexpr int Nn = 65536;
constexpr int VOX_ELEMS = Bb * Cc * R3;    // 33,554,432
constexpr int NCELL = Bb * R3;             // 524,288

// RTNE pack of two f32 into one u32 of 2x bf16 (lo = a, hi = b)
__device__ __forceinline__ unsigned pack_bf16(float a, float b)
{
    unsigned ua = __float_as_uint(a);
    unsigned ub = __float_as_uint(b);
    ua += 0x7FFFu + ((ua >> 16) & 1u);
    ub += 0x7FFFu + ((ub >> 16) & 1u);
    return (ua >> 16) | (ub & 0xFFFF0000u);
}

// ---------------- K1: norm_coords + voxel idx + int counts ----------------
__global__ __launch_bounds__(256) void vox_coords_kernel(
    const float* __restrict__ coords,
    float* __restrict__ norm_out,
    int* __restrict__ idx_out,
    int* __restrict__ cnt)
{
    int t = blockIdx.x * 256 + threadIdx.x;        // t = b*N + i
    int b = t >> 16;
    int i = t & (Nn - 1);

    const float* cp = coords + (size_t)b * 3 * Nn + i;
    float x = cp[0];
    float y = cp[Nn];
    float z = cp[2 * Nn];

    float nx = fminf(fmaxf((x + 1.0f) * 16.0f, 0.0f), 31.0f);
    float ny = fminf(fmaxf((y + 1.0f) * 16.0f, 0.0f), 31.0f);
    float nz = fminf(fmaxf((z + 1.0f) * 16.0f, 0.0f), 31.0f);

    float* np_ = norm_out + (size_t)b * 3 * Nn + i;
    np_[0]      = nx;
    np_[Nn]     = ny;
    np_[2 * Nn] = nz;

    int idx = (int)rintf(nx) * R2 + (int)rintf(ny) * Rr + (int)rintf(nz);

    idx_out[t] = idx;
    atomicAdd(&cnt[(b << 15) + idx], 1);
}

// ---------------- K2: counts -> inverse (empty -> 0) ----------------
__global__ __launch_bounds__(256) void inv_kernel(
    const int* __restrict__ cnt, float* __restrict__ inv)
{
    int t = blockIdx.x * 256 + threadIdx.x;        // total NCELL
    int c = cnt[t];
    inv[t] = c ? 1.0f / (float)c : 0.0f;
}

// ---------------- K3: coalesced read -> LDS transpose -> pk_add_bf16 rows ----------------
__global__ __launch_bounds__(256) void tscatter_atomic_kernel(
    const float* __restrict__ feat,
    const int* __restrict__ idx_ws,
    const float* __restrict__ inv,
    unsigned short* __restrict__ voxT)     // bf16 grid, (cell, ch)
{
    __shared__ float lds[64 * 65];                 // [n][c], stride 65
    __shared__ int   cell_sm[64];
    __shared__ float inv_sm[64];
    int b    = blockIdx.x >> 10;
    int tile = blockIdx.x & 1023;
    int n0   = tile << 6;
    int t    = threadIdx.x;

    if (t < 64) {
        int cell = (b << 15) + idx_ws[(b << 16) + n0 + t];
        cell_sm[t] = cell;
        inv_sm[t]  = inv[cell];                    // random 4B in 2MB table -> L2/L3 hit
    }

#pragma unroll
    for (int k = 0; k < 4; ++k) {
        int c  = (t >> 4) + (k << 4);
        int n4 = (t & 15) << 2;
        float4 v = *(const float4*)(feat + (((size_t)(b * Cc + c)) << 16) + n0 + n4);
        lds[(n4 + 0) * 65 + c] = v.x;
        lds[(n4 + 1) * 65 + c] = v.y;
        lds[(n4 + 2) * 65 + c] = v.z;
        lds[(n4 + 3) * 65 + c] = v.w;
    }
    __syncthreads();

    // per wave instr: lanes 0-31 commit row n, lanes 32-63 row n+1.
    // one pk_add_bf16 = 2 channels; a 128B row = 2 cache lines of atomics.
    int wave = t >> 6, lane = t & 63;
    int hi = lane >> 5;                // 0 or 1
    int m  = lane & 31;                // channel-pair index
#pragma unroll
    for (int k = 0; k < 8; ++k) {
        int n = (wave << 4) + (k << 1) + hi;
        float s  = inv_sm[n];
        float f0 = lds[n * 65 + (m << 1) + 0] * s;
        float f1 = lds[n * 65 + (m << 1) + 1] * s;
        unsigned pk = pack_bf16(f0, f1);
        unsigned short* addr = voxT + ((size_t)cell_sm[n] << 6) + (m << 1);
        asm volatile("global_atomic_pk_add_bf16 %0, %1, off"
                     :: "v"(addr), "v"(pk) : "memory");
    }
}

// ---------------- K4: transpose voxT (b,v,c) bf16 -> vox (b,c,v) f32 ----------------
__global__ __launch_bounds__(256) void transpose_out_kernel(
    const unsigned short* __restrict__ voxT, float* __restrict__ vox)
{
    __shared__ float lds[64 * 65];                 // [v][c], stride 65
    int b    = blockIdx.x >> 9;
    int tile = blockIdx.x & 511;
    int v0   = tile << 6;
    int t    = threadIdx.x;

#pragma unroll
    for (int k = 0; k < 4; ++k) {
        int v  = (t >> 4) + (k << 4);              // 0..63
        int c4 = (t & 15) << 2;                    // 0..60
        ushort4 w = *(const ushort4*)(voxT + (((size_t)(b << 15) + v0 + v) << 6) + c4);
        lds[v * 65 + c4 + 0] = __uint_as_float((unsigned)w.x << 16);
        lds[v * 65 + c4 + 1] = __uint_as_float((unsigned)w.y << 16);
        lds[v * 65 + c4 + 2] = __uint_as_float((unsigned)w.z << 16);
        lds[v * 65 + c4 + 3] = __uint_as_float((unsigned)w.w << 16);
    }
    __syncthreads();

    int wave = t >> 6, lane = t & 63;
#pragma unroll
    for (int k = 0; k < 16; ++k) {
        int c = (wave << 4) + k;
        vox[(((size_t)(b * Cc + c)) << 15) + v0 + lane] = lds[lane * 65 + c];
    }
}

extern "C" void kernel_launch(void* const* d_in, const int* in_sizes, int n_in,
                              void* d_out, int out_size, void* d_ws, size_t ws_size,
                              hipStream_t stream)
{
    const float* features = (const float*)d_in[0];
    const float* coords   = (const float*)d_in[1];

    float* out      = (float*)d_out;
    float* vox      = out;
    float* norm_out = out + VOX_ELEMS;

    // ws layout: cnt (2MB) | inv (2MB) | idx (4MB) | voxT bf16 (67MB)
    char* ws = (char*)d_ws;
    int*            cnt    = (int*)ws;            ws += (size_t)NCELL * 4;
    float*          inv    = (float*)ws;          ws += (size_t)NCELL * 4;
    int*            idx_ws = (int*)ws;            ws += (size_t)Bb * Nn * 4;
    unsigned short* voxT   = (unsigned short*)ws; // NCELL * 64 bf16 = 67 MB

    hipMemsetAsync(cnt, 0, (size_t)NCELL * sizeof(int), stream);
    hipMemsetAsync(voxT, 0, (size_t)NCELL * 64 * sizeof(unsigned short), stream);

    vox_coords_kernel<<<(Bb * Nn) / 256, 256, 0, stream>>>(coords, norm_out, idx_ws, cnt);
    inv_kernel<<<NCELL / 256, 256, 0, stream>>>(cnt, inv);
    tscatter_atomic_kernel<<<Bb * 1024, 256, 0, stream>>>(features, idx_ws, inv, voxT);
    transpose_out_kernel<<<Bb * 512, 256, 0, stream>>>(voxT, vox);
}

// Round 10
// 256.397 us; speedup vs baseline: 2.3890x; 1.0134x over previous
//
#include <hip/hip_runtime.h>

// features: (16, 64, 65536) f32, coords: (16, 3, 65536) f32, resolution = 32
constexpr int Rr = 32;
constexpr int R2 = Rr * Rr;          // 1024
constexpr int R3 = Rr * Rr * Rr;     // 32768
constexpr int Bb = 16;
constexpr int Cc = 64;
constexpr int Nn = 65536;
constexpr int VOX_ELEMS = Bb * Cc * R3;    // 33,554,432
constexpr int NCELL = Bb * R3;             // 524,288

// RTNE pack of two f32 into one u32 of 2x bf16 (lo = a, hi = b)
__device__ __forceinline__ unsigned pack_bf16(float a, float b)
{
    unsigned ua = __float_as_uint(a);
    unsigned ub = __float_as_uint(b);
    ua += 0x7FFFu + ((ua >> 16) & 1u);
    ub += 0x7FFFu + ((ub >> 16) & 1u);
    return (ua >> 16) | (ub & 0xFFFF0000u);
}

// ---------------- K0: zero cnt (2MB) + voxT (67MB) with wide stores ----------------
__global__ __launch_bounds__(256) void zero_ws_kernel(float4* __restrict__ base,
                                                      long total4)
{
    long stride = (long)gridDim.x * 256;
    float4 z = {0.0f, 0.0f, 0.0f, 0.0f};
    for (long i = (long)blockIdx.x * 256 + threadIdx.x; i < total4; i += stride)
        base[i] = z;
}

// ---------------- K1: norm_coords + voxel idx + int counts ----------------
__global__ __launch_bounds__(256) void vox_coords_kernel(
    const float* __restrict__ coords,
    float* __restrict__ norm_out,
    int* __restrict__ idx_out,
    int* __restrict__ cnt)
{
    int t = blockIdx.x * 256 + threadIdx.x;        // t = b*N + i
    int b = t >> 16;
    int i = t & (Nn - 1);

    const float* cp = coords + (size_t)b * 3 * Nn + i;
    float x = cp[0];
    float y = cp[Nn];
    float z = cp[2 * Nn];

    float nx = fminf(fmaxf((x + 1.0f) * 16.0f, 0.0f), 31.0f);
    float ny = fminf(fmaxf((y + 1.0f) * 16.0f, 0.0f), 31.0f);
    float nz = fminf(fmaxf((z + 1.0f) * 16.0f, 0.0f), 31.0f);

    float* np_ = norm_out + (size_t)b * 3 * Nn + i;
    np_[0]      = nx;
    np_[Nn]     = ny;
    np_[2 * Nn] = nz;

    int idx = (int)rintf(nx) * R2 + (int)rintf(ny) * Rr + (int)rintf(nz);

    idx_out[t] = idx;
    atomicAdd(&cnt[(b << 15) + idx], 1);
}

// ---------------- K2: counts -> inverse (empty -> 0) ----------------
__global__ __launch_bounds__(256) void inv_kernel(
    const int* __restrict__ cnt, float* __restrict__ inv)
{
    int t = blockIdx.x * 256 + threadIdx.x;        // total NCELL
    int c = cnt[t];
    inv[t] = c ? 1.0f / (float)c : 0.0f;
}

// ---------------- K3: coalesced read -> LDS transpose -> pk_add_bf16 rows ----------------
__global__ __launch_bounds__(256) void tscatter_atomic_kernel(
    const float* __restrict__ feat,
    const int* __restrict__ idx_ws,
    const float* __restrict__ inv,
    unsigned short* __restrict__ voxT)     // bf16 grid, (cell, ch)
{
    __shared__ float lds[64 * 65];                 // [n][c], stride 65
    __shared__ int   cell_sm[64];
    __shared__ float inv_sm[64];
    int b    = blockIdx.x >> 10;
    int tile = blockIdx.x & 1023;
    int n0   = tile << 6;
    int t    = threadIdx.x;

    if (t < 64) {
        int cell = (b << 15) + idx_ws[(b << 16) + n0 + t];
        cell_sm[t] = cell;
        inv_sm[t]  = inv[cell];                    // random 4B in 2MB table -> L2/L3 hit
    }

#pragma unroll
    for (int k = 0; k < 4; ++k) {
        int c  = (t >> 4) + (k << 4);
        int n4 = (t & 15) << 2;
        float4 v = *(const float4*)(feat + (((size_t)(b * Cc + c)) << 16) + n0 + n4);
        lds[(n4 + 0) * 65 + c] = v.x;
        lds[(n4 + 1) * 65 + c] = v.y;
        lds[(n4 + 2) * 65 + c] = v.z;
        lds[(n4 + 3) * 65 + c] = v.w;
    }
    __syncthreads();

    // per wave instr: lanes 0-31 commit row n, lanes 32-63 row n+1.
    // one pk_add_bf16 = 2 channels; a 128B row = 2 cache lines of atomics.
    int wave = t >> 6, lane = t & 63;
    int hi = lane >> 5;                // 0 or 1
    int m  = lane & 31;                // channel-pair index
#pragma unroll
    for (int k = 0; k < 8; ++k) {
        int n = (wave << 4) + (k << 1) + hi;
        float s  = inv_sm[n];
        float f0 = lds[n * 65 + (m << 1) + 0] * s;
        float f1 = lds[n * 65 + (m << 1) + 1] * s;
        unsigned pk = pack_bf16(f0, f1);
        unsigned short* addr = voxT + ((size_t)cell_sm[n] << 6) + (m << 1);
        asm volatile("global_atomic_pk_add_bf16 %0, %1, off"
                     :: "v"(addr), "v"(pk) : "memory");
    }
}

// ---------------- K4: transpose voxT (b,v,c) bf16 -> vox (b,c,v) f32 ----------------
__global__ __launch_bounds__(256) void transpose_out_kernel(
    const unsigned short* __restrict__ voxT, float* __restrict__ vox)
{
    __shared__ float lds[64 * 65];                 // [v][c], stride 65
    int b    = blockIdx.x >> 9;
    int tile = blockIdx.x & 511;
    int v0   = tile << 6;
    int t    = threadIdx.x;

#pragma unroll
    for (int k = 0; k < 4; ++k) {
        int v  = (t >> 4) + (k << 4);              // 0..63
        int c4 = (t & 15) << 2;                    // 0..60
        ushort4 w = *(const ushort4*)(voxT + (((size_t)(b << 15) + v0 + v) << 6) + c4);
        lds[v * 65 + c4 + 0] = __uint_as_float((unsigned)w.x << 16);
        lds[v * 65 + c4 + 1] = __uint_as_float((unsigned)w.y << 16);
        lds[v * 65 + c4 + 2] = __uint_as_float((unsigned)w.z << 16);
        lds[v * 65 + c4 + 3] = __uint_as_float((unsigned)w.w << 16);
    }
    __syncthreads();

    int wave = t >> 6, lane = t & 63;
#pragma unroll
    for (int k = 0; k < 16; ++k) {
        int c = (wave << 4) + k;
        vox[(((size_t)(b * Cc + c)) << 15) + v0 + lane] = lds[lane * 65 + c];
    }
}

extern "C" void kernel_launch(void* const* d_in, const int* in_sizes, int n_in,
                              void* d_out, int out_size, void* d_ws, size_t ws_size,
                              hipStream_t stream)
{
    const float* features = (const float*)d_in[0];
    const float* coords   = (const float*)d_in[1];

    float* out      = (float*)d_out;
    float* vox      = out;
    float* norm_out = out + VOX_ELEMS;

    // ws layout: cnt (2MB) | inv (2MB) | idx (4MB) | voxT bf16 (67MB)
    char* ws = (char*)d_ws;
    int*            cnt    = (int*)ws;            ws += (size_t)NCELL * 4;
    float*          inv    = (float*)ws;          ws += (size_t)NCELL * 4;
    int*            idx_ws = (int*)ws;            ws += (size_t)Bb * Nn * 4;
    unsigned short* voxT   = (unsigned short*)ws; // NCELL * 64 bf16 = 67 MB

    // zero cnt + voxT ourselves: runtime's captured fill kernel runs at ~435 GB/s (R9).
    // cnt..inv..idx..voxT are contiguous; zeroing cnt+inv+idx+voxT in ONE pass is
    // 75 MB — but idx is written before read and inv fully overwritten, so zeroing
    // them is harmless and keeps a single launch.
    long total4 = ((long)NCELL * 4 + (long)NCELL * 4 + (long)Bb * Nn * 4
                   + (long)NCELL * 64 * 2) / 16;
    zero_ws_kernel<<<2048, 256, 0, stream>>>((float4*)d_ws, total4);

    vox_coords_kernel<<<(Bb * Nn) / 256, 256, 0, stream>>>(coords, norm_out, idx_ws, cnt);
    inv_kernel<<<NCELL / 256, 256, 0, stream>>>(cnt, inv);
    tscatter_atomic_kernel<<<Bb * 1024, 256, 0, stream>>>(features, idx_ws, inv, voxT);
    transpose_out_kernel<<<Bb * 512, 256, 0, stream>>>(voxT, vox);
}

// Round 11
// 224.260 us; speedup vs baseline: 2.7313x; 1.1433x over previous
//
#include <hip/hip_runtime.h>

// features: (16, 64, 65536) f32, coords: (16, 3, 65536) f32, resolution = 32
constexpr int Rr = 32;
constexpr int R2 = Rr * Rr;          // 1024
constexpr int R3 = Rr * Rr * Rr;     // 32768
constexpr int Bb = 16;
constexpr int Cc = 64;
constexpr int Nn = 65536;
constexpr int VOX_ELEMS = Bb * Cc * R3;    // 33,554,432
constexpr int NCELL = Bb * R3;             // 524,288

// RTNE pack of two f32 into one u32 of 2x bf16 (lo = a, hi = b)
__device__ __forceinline__ unsigned pack_bf16(float a, float b)
{
    unsigned ua = __float_as_uint(a);
    unsigned ub = __float_as_uint(b);
    ua += 0x7FFFu + ((ua >> 16) & 1u);
    ub += 0x7FFFu + ((ub >> 16) & 1u);
    return (ua >> 16) | (ub & 0xFFFF0000u);
}

// ---------------- K0: zero cnt (2 MB) ----------------
__global__ __launch_bounds__(256) void zero_cnt_kernel(float4* __restrict__ base)
{
    int i = blockIdx.x * 256 + threadIdx.x;        // NCELL*4/16 elements
    base[i] = float4{0.0f, 0.0f, 0.0f, 0.0f};
}

// ---------------- K1: norm_coords + cell + within-cell rank k ----------------
__global__ __launch_bounds__(256) void vox_coords_kernel(
    const float* __restrict__ coords,
    float* __restrict__ norm_out,
    int* __restrict__ idx_out,
    int* __restrict__ cnt)
{
    int t = blockIdx.x * 256 + threadIdx.x;        // t = b*N + i
    int b = t >> 16;
    int i = t & (Nn - 1);

    const float* cp = coords + (size_t)b * 3 * Nn + i;
    float x = cp[0];
    float y = cp[Nn];
    float z = cp[2 * Nn];

    float nx = fminf(fmaxf((x + 1.0f) * 16.0f, 0.0f), 31.0f);
    float ny = fminf(fmaxf((y + 1.0f) * 16.0f, 0.0f), 31.0f);
    float nz = fminf(fmaxf((z + 1.0f) * 16.0f, 0.0f), 31.0f);

    float* np_ = norm_out + (size_t)b * 3 * Nn + i;
    np_[0]      = nx;
    np_[Nn]     = ny;
    np_[2 * Nn] = nz;

    int idx = (int)rintf(nx) * R2 + (int)rintf(ny) * Rr + (int)rintf(nz);

    int k = atomicAdd(&cnt[(b << 15) + idx], 1);   // within-cell rank
    idx_out[t] = (idx << 3) | min(k, 7);           // 15b cell | 3b clamped rank
}

// ---------------- K2: pre-zero slot3 rows of overflow cells (cnt>4, ~5%) ----------------
__global__ __launch_bounds__(256) void slot3zero_kernel(
    const int* __restrict__ cnt, unsigned short* __restrict__ voxT4)
{
    int g = blockIdx.x * 256 + threadIdx.x;        // NCELL*8 threads
    int cell = g >> 3;
    int p    = g & 7;
    if (cnt[cell] > 4)                             // 2MB table, L2-resident
        *(float4*)(voxT4 + ((size_t)cell << 8) + 192 + (p << 3)) =
            float4{0.0f, 0.0f, 0.0f, 0.0f};        // 8 ushorts = 16 B
}

// ---------------- K3: coalesced read -> LDS transpose -> slotted 128B row stores ----------------
__global__ __launch_bounds__(256) void tscatter_store_kernel(
    const float* __restrict__ feat,
    const int* __restrict__ idx_ws,
    const int* __restrict__ cnt,
    unsigned short* __restrict__ voxT4)    // bf16, [cell][slot0..3][64ch]
{
    __shared__ float lds[64 * 65];                 // [n][c], stride 65
    __shared__ int   dest_sm[64];                  // ushort offset of the point's row
    __shared__ int   at_sm[64];                    // 1 = use atomic (overflow)
    int b    = blockIdx.x >> 10;
    int tile = blockIdx.x & 1023;
    int n0   = tile << 6;
    int t    = threadIdx.x;

    if (t < 64) {
        int e    = idx_ws[(b << 16) + n0 + t];
        int cell = (b << 15) + (e >> 3);
        int k    = e & 7;                          // clamped rank
        int cn   = cnt[cell];                      // final count, L2-hot
        dest_sm[t] = (cell << 8) + (min(k, 3) << 6);   // ushort units
        at_sm[t]   = (k >= 3 && cn > 4) ? 1 : 0;
    }

#pragma unroll
    for (int q = 0; q < 4; ++q) {
        int c  = (t >> 4) + (q << 4);
        int n4 = (t & 15) << 2;
        float4 v = *(const float4*)(feat + (((size_t)(b * Cc + c)) << 16) + n0 + n4);
        lds[(n4 + 0) * 65 + c] = v.x;
        lds[(n4 + 1) * 65 + c] = v.y;
        lds[(n4 + 2) * 65 + c] = v.z;
        lds[(n4 + 3) * 65 + c] = v.w;
    }
    __syncthreads();

    // per wave-instr: lanes 0-31 commit row n, lanes 32-63 row n+1 (128 B bf16 rows)
    int wave = t >> 6, lane = t & 63;
    int hi = lane >> 5;                // 0 or 1
    int m  = lane & 31;                // channel-pair index
#pragma unroll
    for (int kk = 0; kk < 8; ++kk) {
        int n = (wave << 4) + (kk << 1) + hi;
        float f0 = lds[n * 65 + (m << 1) + 0];
        float f1 = lds[n * 65 + (m << 1) + 1];
        unsigned pk = pack_bf16(f0, f1);
        unsigned short* addr = voxT4 + (size_t)dest_sm[n] + (m << 1);
        if (at_sm[n]) {
            asm volatile("global_atomic_pk_add_bf16 %0, %1, off"
                         :: "v"(addr), "v"(pk) : "memory");
        } else {
            *(unsigned*)addr = pk;                 // plain 4 B store, full-line rows
        }
    }
}

// ---------------- K4: merge slots (masked, f32) + divide + transpose to vox ----------------
__global__ __launch_bounds__(256) void merge_transpose_kernel(
    const unsigned short* __restrict__ voxT4,
    const int* __restrict__ cnt,
    float* __restrict__ vox)
{
    __shared__ float lds[64 * 65];                 // [cell][ch], stride 65
    int b    = blockIdx.x >> 9;
    int tile = blockIdx.x & 511;
    int v0   = tile << 6;
    int t    = threadIdx.x;
    int cl   = t >> 2;                             // cell-local 0..63
    int q    = t & 3;                              // ch group of 16

    int cell = (b << 15) + v0 + cl;
    int cn   = cnt[cell];
    int kmax = min(cn, 4);

    float acc[16];
#pragma unroll
    for (int j = 0; j < 16; ++j) acc[j] = 0.0f;

    const unsigned short* base = voxT4 + ((size_t)cell << 8) + (q << 4);
    for (int k = 0; k < kmax; ++k) {
        // 16 ch = 32 B = two uint4 loads
        uint4 w0 = *(const uint4*)(base + (k << 6));
        uint4 w1 = *(const uint4*)(base + (k << 6) + 8);
        const unsigned* w = &w0.x;
#pragma unroll
        for (int j = 0; j < 4; ++j) {
            acc[2 * j + 0] += __uint_as_float(w[j] << 16);
            acc[2 * j + 1] += __uint_as_float(w[j] & 0xFFFF0000u);
        }
        const unsigned* w2 = &w1.x;
#pragma unroll
        for (int j = 0; j < 4; ++j) {
            acc[8 + 2 * j + 0] += __uint_as_float(w2[j] << 16);
            acc[8 + 2 * j + 1] += __uint_as_float(w2[j] & 0xFFFF0000u);
        }
    }

    float inv = cn ? 1.0f / (float)cn : 0.0f;      // empty cell -> 0 (== 0/1e-5)
#pragma unroll
    for (int j = 0; j < 16; ++j)
        lds[cl * 65 + (q << 4) + j] = acc[j] * inv;
    __syncthreads();

    int wave = t >> 6, lane = t & 63;
#pragma unroll
    for (int k = 0; k < 16; ++k) {
        int c = (wave << 4) + k;
        vox[(((size_t)(b * Cc + c)) << 15) + v0 + lane] = lds[lane * 65 + c];
    }
}

extern "C" void kernel_launch(void* const* d_in, const int* in_sizes, int n_in,
                              void* d_out, int out_size, void* d_ws, size_t ws_size,
                              hipStream_t stream)
{
    const float* features = (const float*)d_in[0];
    const float* coords   = (const float*)d_in[1];

    float* out      = (float*)d_out;
    float* vox      = out;
    float* norm_out = out + VOX_ELEMS;

    // ws layout: cnt (2MB) | idx (4MB) | voxT4 bf16 4-slot (268MB, NOT zeroed)
    char* ws = (char*)d_ws;
    int*            cnt    = (int*)ws;            ws += (size_t)NCELL * 4;
    int*            idx_ws = (int*)ws;            ws += (size_t)Bb * Nn * 4;
    unsigned short* voxT4  = (unsigned short*)ws; // NCELL * 4 slots * 64 ch bf16

    zero_cnt_kernel<<<NCELL * 4 / 16 / 256, 256, 0, stream>>>((float4*)cnt);
    vox_coords_kernel<<<(Bb * Nn) / 256, 256, 0, stream>>>(coords, norm_out, idx_ws, cnt);
    slot3zero_kernel<<<NCELL * 8 / 256, 256, 0, stream>>>(cnt, voxT4);
    tscatter_store_kernel<<<Bb * 1024, 256, 0, stream>>>(features, idx_ws, cnt, voxT4);
    merge_transpose_kernel<<<Bb * 512, 256, 0, stream>>>(voxT4, cnt, vox);
}